// Round 4
// baseline (492.178 us; speedup 1.0000x reference)
//
#include <hip/hip_runtime.h>
#include <math.h>

#define BQ 64
#define HH 128
#define EPS 1e-8f

__device__ __forceinline__ float gelu_exact(float x) {
    return 0.5f * x * (1.0f + erff(x * 0.70710678118654752440f));
}

// ---------------------------------------------------------------------------
// FiLM projection: gb[bq, o] = q[bq] . film_w[:,o] + film_b[o]
// grid (BQ, 7): chunk0 -> scale0 (128 o), chunks1-2 -> scale1, chunks3-6 -> scale2
// 256 threads: 2 threads per output, each 384 of the 768 e's.
// ---------------------------------------------------------------------------
__global__ __launch_bounds__(256)
void film2_kernel(const float* __restrict__ qe,
                  const float* __restrict__ fw0, const float* __restrict__ fb0,
                  const float* __restrict__ fw1, const float* __restrict__ fb1,
                  const float* __restrict__ fw2, const float* __restrict__ fb2,
                  float* __restrict__ gb0, float* __restrict__ gb1, float* __restrict__ gb2)
{
    __shared__ float sq[768];
    __shared__ float sP[256];
    const int tid = threadIdx.x, bq = blockIdx.x, chunk = blockIdx.y;
    int s, o0;
    if (chunk == 0)      { s = 0; o0 = 0; }
    else if (chunk <= 2) { s = 1; o0 = (chunk - 1) * 128; }
    else                 { s = 2; o0 = (chunk - 3) * 128; }
    const float* fw  = s == 0 ? fw0 : s == 1 ? fw1 : fw2;
    const float* fbv = s == 0 ? fb0 : s == 1 ? fb1 : fb2;
    float* gb        = s == 0 ? gb0 : s == 1 ? gb1 : gb2;
    const int twoC = 128 << s;   // 128/256/512  (was 256<<s: OOB crash)

    for (int i = tid; i < 768; i += 256) sq[i] = qe[bq * 768 + i];
    __syncthreads();

    const int o = o0 + (tid & 127), half = tid >> 7;
    const int e0 = half * 384;
    float a0 = 0.f, a1 = 0.f;
    #pragma unroll 2
    for (int e = 0; e < 384; e += 2) {
        a0 = fmaf(sq[e0 + e],     fw[(e0 + e) * twoC + o],     a0);
        a1 = fmaf(sq[e0 + e + 1], fw[(e0 + e + 1) * twoC + o], a1);
    }
    sP[tid] = a0 + a1;
    __syncthreads();
    if (tid < 128) {
        int oo = o0 + tid;
        gb[bq * twoC + oo] = sP[tid] + sP[tid + 128] + fbv[oo];
    }
}

// ---------------------------------------------------------------------------
// b2[bq, j] = hid_b[j] + sum_c beta[c] * hid_w[c, j]
// grid (BQ, 3), 256 threads (2 threads per j, split-C)
// ---------------------------------------------------------------------------
__global__ __launch_bounds__(256)
void b2_kernel(const float* __restrict__ gb0, const float* __restrict__ gb1,
               const float* __restrict__ gb2,
               const float* __restrict__ hw0_, const float* __restrict__ hb0,
               const float* __restrict__ hw1_, const float* __restrict__ hb1,
               const float* __restrict__ hw2_, const float* __restrict__ hb2,
               float* __restrict__ b20, float* __restrict__ b21, float* __restrict__ b22)
{
    __shared__ float sBeta[256];
    __shared__ float sP[256];
    const int tid = threadIdx.x, bq = blockIdx.x, s = blockIdx.y;
    const float* gb = s == 0 ? gb0 : s == 1 ? gb1 : gb2;
    const float* hw = s == 0 ? hw0_ : s == 1 ? hw1_ : hw2_;
    const float* hb = s == 0 ? hb0 : s == 1 ? hb1 : hb2;
    float* b2       = s == 0 ? b20 : s == 1 ? b21 : b22;
    const int C = 64 << s;

    for (int i = tid; i < C; i += 256) sBeta[i] = gb[bq * 2 * C + C + i];
    __syncthreads();
    const int j = tid & 127, half = tid >> 7;
    const int c0 = half * (C / 2);
    float acc = 0.f;
    for (int c = 0; c < C / 2; ++c)
        acc = fmaf(sBeta[c0 + c], hw[(c0 + c) * HH + j], acc);
    sP[tid] = acc;
    __syncthreads();
    if (tid < 128) b2[bq * HH + tid] = hb[tid] + sP[tid] + sP[tid + 128];
}

// ---------------------------------------------------------------------------
// Fused FiLM pool. Block = 4 waves, 256-px tile; wave w owns hidden slice
// [32w, 32w+32); 4 px per lane. No barriers in the main loop.
// ---------------------------------------------------------------------------
template<int C, bool WRITE_ATTN>
__device__ __forceinline__
void pool_body(const float* __restrict__ feat, int HW,
               const float* __restrict__ gb, const float* __restrict__ b2,
               const float* __restrict__ hidw, const float* __restrict__ finw,
               const float* __restrict__ finb,
               float* __restrict__ Sout, float* __restrict__ attn_out,
               int bq, int tile,
               float* sW, float* sAttn, float* sPlog, float* sRed)
{
    const int tid = threadIdx.x;
    const int w = tid >> 6, lane = tid & 63;
    const int b = bq >> 5;
    const int hw0 = tile * 256;
    const float* fbase = feat + (size_t)b * C * HW;
    const float* g = gb + bq * 2 * C;              // gamma at [0,C)
    const int pxc = min(hw0 + lane * 4, HW - 4);   // clamped float4 base

    float acc0[32], acc1[32], acc2[32], acc3[32];
    {
        const float4* bp = (const float4*)(b2 + bq * HH + w * 32);
        #pragma unroll
        for (int q = 0; q < 8; ++q) {
            float4 bv = bp[q];
            acc0[q*4+0]=bv.x; acc0[q*4+1]=bv.y; acc0[q*4+2]=bv.z; acc0[q*4+3]=bv.w;
            acc1[q*4+0]=bv.x; acc1[q*4+1]=bv.y; acc1[q*4+2]=bv.z; acc1[q*4+3]=bv.w;
            acc2[q*4+0]=bv.x; acc2[q*4+1]=bv.y; acc2[q*4+2]=bv.z; acc2[q*4+3]=bv.w;
            acc3[q*4+0]=bv.x; acc3[q*4+1]=bv.y; acc3[q*4+2]=bv.z; acc3[q*4+3]=bv.w;
        }
    }

    float* myW = sW + w * 2048;                    // 64c x 32j per-wave slice
    constexpr int NCC = C / 64;
    for (int cc = 0; cc < NCC; ++cc) {
        // stage gamma-scaled weight slice (same-wave write->read, no barrier)
        #pragma unroll 8
        for (int i = 0; i < 32; ++i) {
            int idx = i * 64 + lane;
            int cl = idx >> 5, j = idx & 31;
            int c = cc * 64 + cl;
            myW[idx] = g[c] * hidw[c * HH + w * 32 + j];
        }
        const float* fcol = fbase + (size_t)(cc * 64) * HW + pxc;
        #pragma unroll 2
        for (int c = 0; c < 64; ++c) {
            const float4 fv = *(const float4*)(fcol + (size_t)c * HW);
            const float4* wp = (const float4*)(myW + c * 32);
            #pragma unroll
            for (int q = 0; q < 8; ++q) {
                float4 wv = wp[q];
                acc0[q*4+0] = fmaf(fv.x, wv.x, acc0[q*4+0]);
                acc0[q*4+1] = fmaf(fv.x, wv.y, acc0[q*4+1]);
                acc0[q*4+2] = fmaf(fv.x, wv.z, acc0[q*4+2]);
                acc0[q*4+3] = fmaf(fv.x, wv.w, acc0[q*4+3]);
                acc1[q*4+0] = fmaf(fv.y, wv.x, acc1[q*4+0]);
                acc1[q*4+1] = fmaf(fv.y, wv.y, acc1[q*4+1]);
                acc1[q*4+2] = fmaf(fv.y, wv.z, acc1[q*4+2]);
                acc1[q*4+3] = fmaf(fv.y, wv.w, acc1[q*4+3]);
                acc2[q*4+0] = fmaf(fv.z, wv.x, acc2[q*4+0]);
                acc2[q*4+1] = fmaf(fv.z, wv.y, acc2[q*4+1]);
                acc2[q*4+2] = fmaf(fv.z, wv.z, acc2[q*4+2]);
                acc2[q*4+3] = fmaf(fv.z, wv.w, acc2[q*4+3]);
                acc3[q*4+0] = fmaf(fv.w, wv.x, acc3[q*4+0]);
                acc3[q*4+1] = fmaf(fv.w, wv.y, acc3[q*4+1]);
                acc3[q*4+2] = fmaf(fv.w, wv.z, acc3[q*4+2]);
                acc3[q*4+3] = fmaf(fv.w, wv.w, acc3[q*4+3]);
            }
        }
    }

    // gelu + partial attn logits over this wave's 32 hidden units
    float pl0 = 0.f, pl1 = 0.f, pl2 = 0.f, pl3 = 0.f;
    #pragma unroll
    for (int j = 0; j < 32; ++j) {
        float fwv = finw[w * 32 + j];
        pl0 = fmaf(gelu_exact(acc0[j]), fwv, pl0);
        pl1 = fmaf(gelu_exact(acc1[j]), fwv, pl1);
        pl2 = fmaf(gelu_exact(acc2[j]), fwv, pl2);
        pl3 = fmaf(gelu_exact(acc3[j]), fwv, pl3);
    }
    // layout: sPlog[(w*4+k)*64 + lane] -> px_local = lane*4+k, conflict-free
    sPlog[(w * 4 + 0) * 64 + lane] = pl0;
    sPlog[(w * 4 + 1) * 64 + lane] = pl1;
    sPlog[(w * 4 + 2) * 64 + lane] = pl2;
    sPlog[(w * 4 + 3) * 64 + lane] = pl3;
    __syncthreads();

    {   // combine across waves; thread <-> px_local = tid
        const int k = tid & 3, ln = tid >> 2;
        float lg = finb[0] + sPlog[(0 * 4 + k) * 64 + ln] + sPlog[(1 * 4 + k) * 64 + ln]
                           + sPlog[(2 * 4 + k) * 64 + ln] + sPlog[(3 * 4 + k) * 64 + ln];
        int px = hw0 + tid;
        float a = (px < HW) ? 1.0f / (1.0f + expf(-lg)) : 0.0f;
        sAttn[tid] = a;
        if (WRITE_ATTN && px < HW) attn_out[bq * HW + px] = a;
        float sa = a;
        #pragma unroll
        for (int d = 1; d < 64; d <<= 1) sa += __shfl_xor(sa, d);
        if (lane == 0) sRed[w] = sa;
    }
    __syncthreads();
    if (tid == 0) atomicAdd(&Sout[bq * (C + 1) + C], sRed[0] + sRed[1] + sRed[2] + sRed[3]);

    // S_fc[c]: column-cooperative, coalesced loads, wave shfl-reduce per c
    constexpr int CPW = C / 4;
    for (int ci = 0; ci < CPW; ++ci) {
        const int c = w * CPW + ci;
        const float* fr = fbase + (size_t)c * HW;
        float s = 0.f;
        #pragma unroll
        for (int k = 0; k < 4; ++k) {
            int pxi = lane + 64 * k;
            int gc = min(hw0 + pxi, HW - 1);     // sAttn==0 masks invalid px
            s = fmaf(fr[gc], sAttn[pxi], s);
        }
        #pragma unroll
        for (int d = 1; d < 64; d <<= 1) s += __shfl_xor(s, d);
        if (lane == 0) atomicAdd(&Sout[bq * (C + 1) + c], s);
    }
}

__global__ __launch_bounds__(256, 2)
void pool_fused(const float* __restrict__ feat0, const float* __restrict__ feat1,
                const float* __restrict__ feat2,
                const float* __restrict__ gb0, const float* __restrict__ gb1,
                const float* __restrict__ gb2,
                const float* __restrict__ b20, const float* __restrict__ b21,
                const float* __restrict__ b22,
                const float* __restrict__ hw0_, const float* __restrict__ hw1_,
                const float* __restrict__ hw2_,
                const float* __restrict__ finw0, const float* __restrict__ finb0,
                const float* __restrict__ finw1, const float* __restrict__ finb1,
                const float* __restrict__ finw2, const float* __restrict__ finb2,
                float* __restrict__ S0, float* __restrict__ S1, float* __restrict__ S2,
                float* __restrict__ attn2)
{
    __shared__ float sW[8192];       // 4 waves * 64c * 32j
    __shared__ float sAttn[256];
    __shared__ float sPlog[1024];
    __shared__ float sRed[4];
    const int blk = blockIdx.x;
    if (blk < 128) {                               // scale 2 (heaviest) first
        int bq = blk >> 1, t = blk & 1;
        pool_body<256, true>(feat2, 400, gb2, b22, hw2_, finw2, finb2,
                             S2, attn2, bq, t, sW, sAttn, sPlog, sRed);
    } else if (blk < 128 + 448) {
        int bb = blk - 128; int bq = bb / 7, t = bb % 7;
        pool_body<128, false>(feat1, 1600, gb1, b21, hw1_, finw1, finb1,
                              S1, nullptr, bq, t, sW, sAttn, sPlog, sRed);
    } else {
        int bb = blk - 576; int bq = bb / 25, t = bb % 25;
        pool_body<64, false>(feat0, 6400, gb0, b20, hw0_, finw0, finb0,
                             S0, nullptr, bq, t, sW, sAttn, sPlog, sRed);
    }
}

// ---------------------------------------------------------------------------
// MLP layer 1 (pre-gelu): grid (BQ, 4), 128 outputs per block, 2 thr/output
// ---------------------------------------------------------------------------
__global__ __launch_bounds__(256)
void mlp1_kernel(const float* __restrict__ S0, const float* __restrict__ S1,
                 const float* __restrict__ S2,
                 const float* __restrict__ gb0, const float* __restrict__ gb1,
                 const float* __restrict__ gb2,
                 const float* __restrict__ attn2,
                 const float* __restrict__ w1, const float* __restrict__ b1,
                 float* __restrict__ X1)
{
    __shared__ float sCat[848];
    __shared__ float sP[256];
    const int tid = threadIdx.x, bq = blockIdx.x;

    for (int i = tid; i < 448; i += 256) {
        int sc, c;
        if (i < 64)       { sc = 0; c = i; }
        else if (i < 192) { sc = 1; c = i - 64; }
        else              { sc = 2; c = i - 192; }
        const int C = 64 << sc;
        const float* So = (sc == 0) ? S0 : (sc == 1) ? S1 : S2;
        const float* g  = (sc == 0) ? gb0 : (sc == 1) ? gb1 : gb2;
        float Sa = So[bq * (C + 1) + C];
        float Sf = So[bq * (C + 1) + c];
        float gamma = g[bq * 2 * C + c];
        float beta  = g[bq * 2 * C + C + c];
        sCat[i] = (gamma * Sf + beta * Sa) / (Sa + EPS);
    }
    for (int i = tid; i < 400; i += 256) sCat[448 + i] = attn2[bq * 400 + i];
    __syncthreads();

    const int o = blockIdx.y * 128 + (tid & 127), half = tid >> 7;
    const int k0 = half * 424;
    float a0 = 0.f, a1 = 0.f;
    #pragma unroll 2
    for (int k = 0; k < 424; k += 2) {
        a0 = fmaf(sCat[k0 + k],     w1[(k0 + k) * 512 + o],     a0);
        a1 = fmaf(sCat[k0 + k + 1], w1[(k0 + k + 1) * 512 + o], a1);
    }
    sP[tid] = a0 + a1;
    __syncthreads();
    if (tid < 128) {
        int oo = blockIdx.y * 128 + tid;
        X1[bq * 512 + oo] = sP[tid] + sP[tid + 128] + b1[oo];
    }
}

// ---------------------------------------------------------------------------
// MLP layers 2+3. grid BQ, 256 threads
// ---------------------------------------------------------------------------
__global__ __launch_bounds__(256)
void mlp23_kernel(const float* __restrict__ X1,
                  const float* __restrict__ w2, const float* __restrict__ b2,
                  const float* __restrict__ w3, const float* __restrict__ b3,
                  float* __restrict__ out)
{
    __shared__ float sX1[512];
    __shared__ float sX2[256];
    __shared__ float sR[4];
    const int tid = threadIdx.x, bq = blockIdx.x;
    for (int i = tid; i < 512; i += 256) sX1[i] = gelu_exact(X1[bq * 512 + i]);
    __syncthreads();
    float a0 = b2[tid], a1 = 0.f, a2 = 0.f, a3 = 0.f;
    #pragma unroll 4
    for (int k = 0; k < 512; k += 4) {
        a0 = fmaf(sX1[k],     w2[(k)     * 256 + tid], a0);
        a1 = fmaf(sX1[k + 1], w2[(k + 1) * 256 + tid], a1);
        a2 = fmaf(sX1[k + 2], w2[(k + 2) * 256 + tid], a2);
        a3 = fmaf(sX1[k + 3], w2[(k + 3) * 256 + tid], a3);
    }
    sX2[tid] = gelu_exact((a0 + a1) + (a2 + a3));
    __syncthreads();
    float p = sX2[tid] * w3[tid];
    #pragma unroll
    for (int d = 1; d < 64; d <<= 1) p += __shfl_xor(p, d);
    if ((tid & 63) == 0) sR[tid >> 6] = p;
    __syncthreads();
    if (tid == 0) out[bq] = sR[0] + sR[1] + sR[2] + sR[3] + b3[0];
}

// ---------------------------------------------------------------------------
extern "C" void kernel_launch(void* const* d_in, const int* in_sizes, int n_in,
                              void* d_out, int out_size, void* d_ws, size_t ws_size,
                              hipStream_t stream)
{
    const float* feat0 = (const float*)d_in[0];
    const float* feat1 = (const float*)d_in[1];
    const float* feat2 = (const float*)d_in[2];
    const float* qe    = (const float*)d_in[3];
    const float* film_w0 = (const float*)d_in[4];
    const float* film_b0 = (const float*)d_in[5];
    const float* hid_w0  = (const float*)d_in[6];
    const float* hid_b0  = (const float*)d_in[7];
    const float* fin_w0  = (const float*)d_in[8];
    const float* fin_b0  = (const float*)d_in[9];
    const float* film_w1 = (const float*)d_in[10];
    const float* film_b1 = (const float*)d_in[11];
    const float* hid_w1  = (const float*)d_in[12];
    const float* hid_b1  = (const float*)d_in[13];
    const float* fin_w1  = (const float*)d_in[14];
    const float* fin_b1  = (const float*)d_in[15];
    const float* film_w2 = (const float*)d_in[16];
    const float* film_b2 = (const float*)d_in[17];
    const float* hid_w2  = (const float*)d_in[18];
    const float* hid_b2  = (const float*)d_in[19];
    const float* fin_w2  = (const float*)d_in[20];
    const float* fin_b2  = (const float*)d_in[21];
    const float* mlp_w1  = (const float*)d_in[22];
    const float* mlp_b1  = (const float*)d_in[23];
    const float* mlp_w2  = (const float*)d_in[24];
    const float* mlp_b2  = (const float*)d_in[25];
    const float* mlp_w3  = (const float*)d_in[26];
    const float* mlp_b3  = (const float*)d_in[27];

    float* ws = (float*)d_ws;
    float* S0    = ws;              // [64][65]
    float* S1    = ws + 4160;       // [64][129]
    float* S2    = ws + 12416;      // [64][257]   (Sout end 28864)
    float* gb0   = ws + 28864;      // [64][128]
    float* gb1   = ws + 37056;      // [64][256]
    float* gb2   = ws + 53440;      // [64][512]
    float* b20   = ws + 86208;      // [64][128]
    float* b21   = ws + 94400;
    float* b22   = ws + 102592;
    float* attn2 = ws + 110784;     // [64][400]
    float* X1    = ws + 136384;     // [64][512]

    hipMemsetAsync(d_ws, 0, 28864 * sizeof(float), stream);

    film2_kernel<<<dim3(BQ, 7), 256, 0, stream>>>(
        qe, film_w0, film_b0, film_w1, film_b1, film_w2, film_b2,
        gb0, gb1, gb2);

    b2_kernel<<<dim3(BQ, 3), 256, 0, stream>>>(
        gb0, gb1, gb2,
        hid_w0, hid_b0, hid_w1, hid_b1, hid_w2, hid_b2,
        b20, b21, b22);

    pool_fused<<<2176, 256, 0, stream>>>(
        feat0, feat1, feat2,
        gb0, gb1, gb2, b20, b21, b22,
        hid_w0, hid_w1, hid_w2,
        fin_w0, fin_b0, fin_w1, fin_b1, fin_w2, fin_b2,
        S0, S1, S2, attn2);

    mlp1_kernel<<<dim3(BQ, 4), 256, 0, stream>>>(
        S0, S1, S2, gb0, gb1, gb2, attn2, mlp_w1, mlp_b1, X1);

    mlp23_kernel<<<BQ, 256, 0, stream>>>(
        X1, mlp_w2, mlp_b2, mlp_w3, mlp_b3, (float*)d_out);
}

// Round 5
// 429.599 us; speedup vs baseline: 1.1457x; 1.1457x over previous
//
#include <hip/hip_runtime.h>
#include <math.h>

#define BQ 64
#define HH 128
#define EPS 1e-8f

__device__ __forceinline__ float gelu_exact(float x) {
    return 0.5f * x * (1.0f + erff(x * 0.70710678118654752440f));
}

// ---------------------------------------------------------------------------
// FiLM projection: gb[bq, o] = q[bq] . film_w[:,o] + film_b[o]
// grid (BQ, 7): chunk0 -> scale0 (128 o), chunks1-2 -> scale1, chunks3-6 -> scale2
// ---------------------------------------------------------------------------
__global__ __launch_bounds__(256)
void film2_kernel(const float* __restrict__ qe,
                  const float* __restrict__ fw0, const float* __restrict__ fb0,
                  const float* __restrict__ fw1, const float* __restrict__ fb1,
                  const float* __restrict__ fw2, const float* __restrict__ fb2,
                  float* __restrict__ gb0, float* __restrict__ gb1, float* __restrict__ gb2)
{
    __shared__ float sq[768];
    __shared__ float sP[256];
    const int tid = threadIdx.x, bq = blockIdx.x, chunk = blockIdx.y;
    int s, o0;
    if (chunk == 0)      { s = 0; o0 = 0; }
    else if (chunk <= 2) { s = 1; o0 = (chunk - 1) * 128; }
    else                 { s = 2; o0 = (chunk - 3) * 128; }
    const float* fw  = s == 0 ? fw0 : s == 1 ? fw1 : fw2;
    const float* fbv = s == 0 ? fb0 : s == 1 ? fb1 : fb2;
    float* gb        = s == 0 ? gb0 : s == 1 ? gb1 : gb2;
    const int twoC = 128 << s;   // 128/256/512

    for (int i = tid; i < 768; i += 256) sq[i] = qe[bq * 768 + i];
    __syncthreads();

    const int o = o0 + (tid & 127), half = tid >> 7;
    const int e0 = half * 384;
    float a0 = 0.f, a1 = 0.f;
    #pragma unroll 2
    for (int e = 0; e < 384; e += 2) {
        a0 = fmaf(sq[e0 + e],     fw[(e0 + e) * twoC + o],     a0);
        a1 = fmaf(sq[e0 + e + 1], fw[(e0 + e + 1) * twoC + o], a1);
    }
    sP[tid] = a0 + a1;
    __syncthreads();
    if (tid < 128) {
        int oo = o0 + tid;
        gb[bq * twoC + oo] = sP[tid] + sP[tid + 128] + fbv[oo];
    }
}

// ---------------------------------------------------------------------------
// b2[bq, j] = hid_b[j] + sum_c beta[c] * hid_w[c, j]
// ---------------------------------------------------------------------------
__global__ __launch_bounds__(256)
void b2_kernel(const float* __restrict__ gb0, const float* __restrict__ gb1,
               const float* __restrict__ gb2,
               const float* __restrict__ hw0_, const float* __restrict__ hb0,
               const float* __restrict__ hw1_, const float* __restrict__ hb1,
               const float* __restrict__ hw2_, const float* __restrict__ hb2,
               float* __restrict__ b20, float* __restrict__ b21, float* __restrict__ b22)
{
    __shared__ float sBeta[256];
    __shared__ float sP[256];
    const int tid = threadIdx.x, bq = blockIdx.x, s = blockIdx.y;
    const float* gb = s == 0 ? gb0 : s == 1 ? gb1 : gb2;
    const float* hw = s == 0 ? hw0_ : s == 1 ? hw1_ : hw2_;
    const float* hb = s == 0 ? hb0 : s == 1 ? hb1 : hb2;
    float* b2       = s == 0 ? b20 : s == 1 ? b21 : b22;
    const int C = 64 << s;

    for (int i = tid; i < C; i += 256) sBeta[i] = gb[bq * 2 * C + C + i];
    __syncthreads();
    const int j = tid & 127, half = tid >> 7;
    const int c0 = half * (C / 2);
    float acc = 0.f;
    for (int c = 0; c < C / 2; ++c)
        acc = fmaf(sBeta[c0 + c], hw[(c0 + c) * HH + j], acc);
    sP[tid] = acc;
    __syncthreads();
    if (tid < 128) b2[bq * HH + tid] = hb[tid] + sP[tid] + sP[tid + 128];
}

// ---------------------------------------------------------------------------
// Fused FiLM pool. Block = 4 waves, 128-px tile, 2 px/lane.
// gamma folded into FEAT (not W) so W and gamma are wave-uniform -> SGPR
// broadcast (v_fma v,v,s), zero LDS in the main loop, acc = 64 VGPR (no spill).
// ---------------------------------------------------------------------------
template<int C, bool WRITE_ATTN>
__device__ __forceinline__
void pool_body(const float* __restrict__ feat, int HW,
               const float* __restrict__ gb, const float* __restrict__ b2,
               const float* __restrict__ hidw, const float* __restrict__ finw,
               const float* __restrict__ finb,
               float* __restrict__ Sout, float* __restrict__ attn_out,
               int bq, int tile,
               float* sAttn, float* sPlog, float* sRed)
{
    const int tid = threadIdx.x;
    const int wu = __builtin_amdgcn_readfirstlane(tid >> 6);  // wave-uniform wave id
    const int lane = tid & 63;
    const int b = bq >> 5;
    const int hw0 = tile * 128;
    const float* fbase = feat + (size_t)b * C * HW;
    const float* g = gb + bq * 2 * C;              // gamma at [0,C) — uniform loads
    const int pxc = min(hw0 + lane * 2, HW - 2);   // clamped float2 base (HW even)

    float acc0[32], acc1[32];
    {
        const float* bp = b2 + bq * HH + wu * 32;  // uniform
        #pragma unroll
        for (int j = 0; j < 32; ++j) { float bv = bp[j]; acc0[j] = bv; acc1[j] = bv; }
    }

    const float* wrow = hidw + wu * 32;            // uniform base
    const float* fp = fbase + pxc;                 // per-lane
    #pragma unroll 2
    for (int c = 0; c < C; ++c) {
        const float gam = g[c];                              // SGPR
        const float2 fv = *(const float2*)(fp + (size_t)c * HW);
        const float f0 = gam * fv.x, f1 = gam * fv.y;
        const float* wr = wrow + (size_t)c * HH;             // uniform -> s_load
        #pragma unroll
        for (int j = 0; j < 32; ++j) {
            const float wv = wr[j];
            acc0[j] = fmaf(f0, wv, acc0[j]);
            acc1[j] = fmaf(f1, wv, acc1[j]);
        }
    }

    // gelu + partial attn logits over this wave's 32 hidden units
    float pl0 = 0.f, pl1 = 0.f;
    #pragma unroll
    for (int j = 0; j < 32; ++j) {
        const float fwv = finw[wu * 32 + j];       // uniform
        pl0 = fmaf(gelu_exact(acc0[j]), fwv, pl0);
        pl1 = fmaf(gelu_exact(acc1[j]), fwv, pl1);
    }
    sPlog[wu * 128 + lane * 2]     = pl0;
    sPlog[wu * 128 + lane * 2 + 1] = pl1;
    __syncthreads();

    if (tid < 128) {                               // combine waves; px_local = tid
        float lg = finb[0] + sPlog[tid] + sPlog[128 + tid] + sPlog[256 + tid] + sPlog[384 + tid];
        int px = hw0 + tid;
        float a = (px < HW) ? 1.0f / (1.0f + expf(-lg)) : 0.0f;
        sAttn[tid] = a;
        if (WRITE_ATTN && px < HW) attn_out[bq * HW + px] = a;
        float sa = a;
        #pragma unroll
        for (int d = 1; d < 64; d <<= 1) sa += __shfl_xor(sa, d);
        if ((tid & 63) == 0) sRed[tid >> 6] = sa;
    }
    __syncthreads();
    if (tid == 0) atomicAdd(&Sout[bq * (C + 1) + C], sRed[0] + sRed[1]);

    // S_fc[c]: column-cooperative, coalesced loads, wave shfl-reduce per c
    constexpr int CPW = C / 4;
    for (int ci = 0; ci < CPW; ++ci) {
        const int c = wu * CPW + ci;
        const float* fr = fbase + (size_t)c * HW;
        float s = 0.f;
        #pragma unroll
        for (int k = 0; k < 2; ++k) {
            int pxi = lane + 64 * k;
            int gc = min(hw0 + pxi, HW - 1);       // sAttn==0 masks invalid px
            s = fmaf(fr[gc], sAttn[pxi], s);
        }
        #pragma unroll
        for (int d = 1; d < 64; d <<= 1) s += __shfl_xor(s, d);
        if (lane == 0) atomicAdd(&Sout[bq * (C + 1) + c], s);
    }
}

__global__ __launch_bounds__(256)
void pool_fused(const float* __restrict__ feat0, const float* __restrict__ feat1,
                const float* __restrict__ feat2,
                const float* __restrict__ gb0, const float* __restrict__ gb1,
                const float* __restrict__ gb2,
                const float* __restrict__ b20, const float* __restrict__ b21,
                const float* __restrict__ b22,
                const float* __restrict__ hw0_, const float* __restrict__ hw1_,
                const float* __restrict__ hw2_,
                const float* __restrict__ finw0, const float* __restrict__ finb0,
                const float* __restrict__ finw1, const float* __restrict__ finb1,
                const float* __restrict__ finw2, const float* __restrict__ finb2,
                float* __restrict__ S0, float* __restrict__ S1, float* __restrict__ S2,
                float* __restrict__ attn2)
{
    __shared__ float sAttn[128];
    __shared__ float sPlog[512];
    __shared__ float sRed[2];
    const int blk = blockIdx.x;
    if (blk < 256) {                               // scale 2 (heaviest) first
        int bq = blk >> 2, t = blk & 3;            // 4 tiles of 128 px (400 -> pad)
        pool_body<256, true>(feat2, 400, gb2, b22, hw2_, finw2, finb2,
                             S2, attn2, bq, t, sAttn, sPlog, sRed);
    } else if (blk < 256 + 832) {
        int bb = blk - 256; int bq = bb / 13, t = bb % 13;   // 13 tiles (1600)
        pool_body<128, false>(feat1, 1600, gb1, b21, hw1_, finw1, finb1,
                              S1, nullptr, bq, t, sAttn, sPlog, sRed);
    } else {
        int bb = blk - 1088; int bq = bb / 50, t = bb % 50;  // 50 tiles (6400)
        pool_body<64, false>(feat0, 6400, gb0, b20, hw0_, finw0, finb0,
                             S0, nullptr, bq, t, sAttn, sPlog, sRed);
    }
}

// ---------------------------------------------------------------------------
// MLP layer 1 (pre-gelu): grid (BQ, 4), 128 outputs per block, 2 thr/output
// ---------------------------------------------------------------------------
__global__ __launch_bounds__(256)
void mlp1_kernel(const float* __restrict__ S0, const float* __restrict__ S1,
                 const float* __restrict__ S2,
                 const float* __restrict__ gb0, const float* __restrict__ gb1,
                 const float* __restrict__ gb2,
                 const float* __restrict__ attn2,
                 const float* __restrict__ w1, const float* __restrict__ b1,
                 float* __restrict__ X1)
{
    __shared__ float sCat[848];
    __shared__ float sP[256];
    const int tid = threadIdx.x, bq = blockIdx.x;

    for (int i = tid; i < 448; i += 256) {
        int sc, c;
        if (i < 64)       { sc = 0; c = i; }
        else if (i < 192) { sc = 1; c = i - 64; }
        else              { sc = 2; c = i - 192; }
        const int C = 64 << sc;
        const float* So = (sc == 0) ? S0 : (sc == 1) ? S1 : S2;
        const float* g  = (sc == 0) ? gb0 : (sc == 1) ? gb1 : gb2;
        float Sa = So[bq * (C + 1) + C];
        float Sf = So[bq * (C + 1) + c];
        float gamma = g[bq * 2 * C + c];
        float beta  = g[bq * 2 * C + C + c];
        sCat[i] = (gamma * Sf + beta * Sa) / (Sa + EPS);
    }
    for (int i = tid; i < 400; i += 256) sCat[448 + i] = attn2[bq * 400 + i];
    __syncthreads();

    const int o = blockIdx.y * 128 + (tid & 127), half = tid >> 7;
    const int k0 = half * 424;
    float a0 = 0.f, a1 = 0.f;
    #pragma unroll 2
    for (int k = 0; k < 424; k += 2) {
        a0 = fmaf(sCat[k0 + k],     w1[(k0 + k) * 512 + o],     a0);
        a1 = fmaf(sCat[k0 + k + 1], w1[(k0 + k + 1) * 512 + o], a1);
    }
    sP[tid] = a0 + a1;
    __syncthreads();
    if (tid < 128) {
        int oo = blockIdx.y * 128 + tid;
        X1[bq * 512 + oo] = sP[tid] + sP[tid + 128] + b1[oo];
    }
}

// ---------------------------------------------------------------------------
// MLP layers 2+3. grid BQ, 256 threads
// ---------------------------------------------------------------------------
__global__ __launch_bounds__(256)
void mlp23_kernel(const float* __restrict__ X1,
                  const float* __restrict__ w2, const float* __restrict__ b2,
                  const float* __restrict__ w3, const float* __restrict__ b3,
                  float* __restrict__ out)
{
    __shared__ float sX1[512];
    __shared__ float sX2[256];
    __shared__ float sR[4];
    const int tid = threadIdx.x, bq = blockIdx.x;
    for (int i = tid; i < 512; i += 256) sX1[i] = gelu_exact(X1[bq * 512 + i]);
    __syncthreads();
    float a0 = b2[tid], a1 = 0.f, a2 = 0.f, a3 = 0.f;
    #pragma unroll 4
    for (int k = 0; k < 512; k += 4) {
        a0 = fmaf(sX1[k],     w2[(k)     * 256 + tid], a0);
        a1 = fmaf(sX1[k + 1], w2[(k + 1) * 256 + tid], a1);
        a2 = fmaf(sX1[k + 2], w2[(k + 2) * 256 + tid], a2);
        a3 = fmaf(sX1[k + 3], w2[(k + 3) * 256 + tid], a3);
    }
    sX2[tid] = gelu_exact((a0 + a1) + (a2 + a3));
    __syncthreads();
    float p = sX2[tid] * w3[tid];
    #pragma unroll
    for (int d = 1; d < 64; d <<= 1) p += __shfl_xor(p, d);
    if ((tid & 63) == 0) sR[tid >> 6] = p;
    __syncthreads();
    if (tid == 0) out[bq] = sR[0] + sR[1] + sR[2] + sR[3] + b3[0];
}

// ---------------------------------------------------------------------------
extern "C" void kernel_launch(void* const* d_in, const int* in_sizes, int n_in,
                              void* d_out, int out_size, void* d_ws, size_t ws_size,
                              hipStream_t stream)
{
    const float* feat0 = (const float*)d_in[0];
    const float* feat1 = (const float*)d_in[1];
    const float* feat2 = (const float*)d_in[2];
    const float* qe    = (const float*)d_in[3];
    const float* film_w0 = (const float*)d_in[4];
    const float* film_b0 = (const float*)d_in[5];
    const float* hid_w0  = (const float*)d_in[6];
    const float* hid_b0  = (const float*)d_in[7];
    const float* fin_w0  = (const float*)d_in[8];
    const float* fin_b0  = (const float*)d_in[9];
    const float* film_w1 = (const float*)d_in[10];
    const float* film_b1 = (const float*)d_in[11];
    const float* hid_w1  = (const float*)d_in[12];
    const float* hid_b1  = (const float*)d_in[13];
    const float* fin_w1  = (const float*)d_in[14];
    const float* fin_b1  = (const float*)d_in[15];
    const float* film_w2 = (const float*)d_in[16];
    const float* film_b2 = (const float*)d_in[17];
    const float* hid_w2  = (const float*)d_in[18];
    const float* hid_b2  = (const float*)d_in[19];
    const float* fin_w2  = (const float*)d_in[20];
    const float* fin_b2  = (const float*)d_in[21];
    const float* mlp_w1  = (const float*)d_in[22];
    const float* mlp_b1  = (const float*)d_in[23];
    const float* mlp_w2  = (const float*)d_in[24];
    const float* mlp_b2  = (const float*)d_in[25];
    const float* mlp_w3  = (const float*)d_in[26];
    const float* mlp_b3  = (const float*)d_in[27];

    float* ws = (float*)d_ws;
    float* S0    = ws;              // [64][65]
    float* S1    = ws + 4160;       // [64][129]
    float* S2    = ws + 12416;      // [64][257]   (Sout end 28864)
    float* gb0   = ws + 28864;      // [64][128]
    float* gb1   = ws + 37056;      // [64][256]
    float* gb2   = ws + 53440;      // [64][512]
    float* b20   = ws + 86208;      // [64][128]
    float* b21   = ws + 94400;
    float* b22   = ws + 102592;
    float* attn2 = ws + 110784;     // [64][400]
    float* X1    = ws + 136384;     // [64][512]

    hipMemsetAsync(d_ws, 0, 28864 * sizeof(float), stream);

    film2_kernel<<<dim3(BQ, 7), 256, 0, stream>>>(
        qe, film_w0, film_b0, film_w1, film_b1, film_w2, film_b2,
        gb0, gb1, gb2);

    b2_kernel<<<dim3(BQ, 3), 256, 0, stream>>>(
        gb0, gb1, gb2,
        hid_w0, hid_b0, hid_w1, hid_b1, hid_w2, hid_b2,
        b20, b21, b22);

    pool_fused<<<4288, 256, 0, stream>>>(
        feat0, feat1, feat2,
        gb0, gb1, gb2, b20, b21, b22,
        hid_w0, hid_w1, hid_w2,
        fin_w0, fin_b0, fin_w1, fin_b1, fin_w2, fin_b2,
        S0, S1, S2, attn2);

    mlp1_kernel<<<dim3(BQ, 4), 256, 0, stream>>>(
        S0, S1, S2, gb0, gb1, gb2, attn2, mlp_w1, mlp_b1, X1);

    mlp23_kernel<<<BQ, 256, 0, stream>>>(
        X1, mlp_w2, mlp_b2, mlp_w3, mlp_b3, (float*)d_out);
}

// Round 6
// 375.410 us; speedup vs baseline: 1.3110x; 1.1443x over previous
//
#include <hip/hip_runtime.h>
#include <math.h>

#define BQ 64
#define HH 128
#define EPS 1e-8f

__device__ __forceinline__ float gelu_exact(float x) {
    return 0.5f * x * (1.0f + erff(x * 0.70710678118654752440f));
}

// ---------------------------------------------------------------------------
// FiLM projection: gb[bq, o] = q[bq] . film_w[:,o] + film_b[o]
// grid (BQ, 7): chunk0 -> scale0 (128 o), chunks1-2 -> scale1, chunks3-6 -> scale2
// ---------------------------------------------------------------------------
__global__ __launch_bounds__(256)
void film2_kernel(const float* __restrict__ qe,
                  const float* __restrict__ fw0, const float* __restrict__ fb0,
                  const float* __restrict__ fw1, const float* __restrict__ fb1,
                  const float* __restrict__ fw2, const float* __restrict__ fb2,
                  float* __restrict__ gb0, float* __restrict__ gb1, float* __restrict__ gb2)
{
    __shared__ float sq[768];
    __shared__ float sP[256];
    const int tid = threadIdx.x, bq = blockIdx.x, chunk = blockIdx.y;
    int s, o0;
    if (chunk == 0)      { s = 0; o0 = 0; }
    else if (chunk <= 2) { s = 1; o0 = (chunk - 1) * 128; }
    else                 { s = 2; o0 = (chunk - 3) * 128; }
    const float* fw  = s == 0 ? fw0 : s == 1 ? fw1 : fw2;
    const float* fbv = s == 0 ? fb0 : s == 1 ? fb1 : fb2;
    float* gb        = s == 0 ? gb0 : s == 1 ? gb1 : gb2;
    const int twoC = 128 << s;   // 128/256/512

    for (int i = tid; i < 768; i += 256) sq[i] = qe[bq * 768 + i];
    __syncthreads();

    const int o = o0 + (tid & 127), half = tid >> 7;
    const int e0 = half * 384;
    float a0 = 0.f, a1 = 0.f;
    #pragma unroll 2
    for (int e = 0; e < 384; e += 2) {
        a0 = fmaf(sq[e0 + e],     fw[(e0 + e) * twoC + o],     a0);
        a1 = fmaf(sq[e0 + e + 1], fw[(e0 + e + 1) * twoC + o], a1);
    }
    sP[tid] = a0 + a1;
    __syncthreads();
    if (tid < 128) {
        int oo = o0 + tid;
        gb[bq * twoC + oo] = sP[tid] + sP[tid + 128] + fbv[oo];
    }
}

// ---------------------------------------------------------------------------
// b2[bq, j] = hid_b[j] + sum_c beta[c] * hid_w[c, j]
// ---------------------------------------------------------------------------
__global__ __launch_bounds__(256)
void b2_kernel(const float* __restrict__ gb0, const float* __restrict__ gb1,
               const float* __restrict__ gb2,
               const float* __restrict__ hw0_, const float* __restrict__ hb0,
               const float* __restrict__ hw1_, const float* __restrict__ hb1,
               const float* __restrict__ hw2_, const float* __restrict__ hb2,
               float* __restrict__ b20, float* __restrict__ b21, float* __restrict__ b22)
{
    __shared__ float sBeta[256];
    __shared__ float sP[256];
    const int tid = threadIdx.x, bq = blockIdx.x, s = blockIdx.y;
    const float* gb = s == 0 ? gb0 : s == 1 ? gb1 : gb2;
    const float* hw = s == 0 ? hw0_ : s == 1 ? hw1_ : hw2_;
    const float* hb = s == 0 ? hb0 : s == 1 ? hb1 : hb2;
    float* b2       = s == 0 ? b20 : s == 1 ? b21 : b22;
    const int C = 64 << s;

    for (int i = tid; i < C; i += 256) sBeta[i] = gb[bq * 2 * C + C + i];
    __syncthreads();
    const int j = tid & 127, half = tid >> 7;
    const int c0 = half * (C / 2);
    float acc = 0.f;
    for (int c = 0; c < C / 2; ++c)
        acc = fmaf(sBeta[c0 + c], hw[(c0 + c) * HH + j], acc);
    sP[tid] = acc;
    __syncthreads();
    if (tid < 128) b2[bq * HH + tid] = hb[tid] + sP[tid] + sP[tid + 128];
}

// ---------------------------------------------------------------------------
// Fused FiLM pool. Block = 4 waves, 128-px tile, 2 px/lane, wave owns 32 j.
// gamma folded into FEAT; W/gamma wave-uniform (SGPR). 4-deep feat prefetch
// pipeline (f0..f3 named regs) hides VMEM latency under independent FMAs.
// ---------------------------------------------------------------------------
template<int C, bool WRITE_ATTN>
__device__ __forceinline__
void pool_body(const float* __restrict__ feat, int HW,
               const float* __restrict__ gb, const float* __restrict__ b2,
               const float* __restrict__ hidw, const float* __restrict__ finw,
               const float* __restrict__ finb,
               float* __restrict__ Sout, float* __restrict__ attn_out,
               int bq, int tile,
               float* sAttn, float* sPlog, float* sRed)
{
    const int tid = threadIdx.x;
    const int wu = __builtin_amdgcn_readfirstlane(tid >> 6);  // wave-uniform wave id
    const int lane = tid & 63;
    const int b = bq >> 5;
    const int hw0 = tile * 128;
    const float* fbase = feat + (size_t)b * C * HW;
    const float* g = gb + bq * 2 * C;              // gamma at [0,C) — uniform
    const int pxc = min(hw0 + lane * 2, HW - 2);   // clamped float2 base (HW even)

    float acc0[32], acc1[32];
    {
        const float* bp = b2 + bq * HH + wu * 32;  // uniform
        #pragma unroll
        for (int j = 0; j < 32; ++j) { float bv = bp[j]; acc0[j] = bv; acc1[j] = bv; }
    }

    const float* wrow = hidw + wu * 32;            // uniform base
    const float* fp = fbase + pxc;                 // per-lane

    // 4-deep rotating prefetch of feat columns
    float2 f0 = *(const float2*)(fp);
    float2 f1 = *(const float2*)(fp + (size_t)1 * HW);
    float2 f2 = *(const float2*)(fp + (size_t)2 * HW);
    float2 f3 = *(const float2*)(fp + (size_t)3 * HW);

#define POOL_STEP(CC, FREG, DOLOAD, CLOAD)                                   \
    {                                                                        \
        const float gam = g[(CC)];                                           \
        const float fa = gam * FREG.x, fb_ = gam * FREG.y;                   \
        if (DOLOAD) FREG = *(const float2*)(fp + (size_t)(CLOAD) * HW);      \
        const float* wr = wrow + (size_t)(CC) * HH;                          \
        _Pragma("unroll")                                                    \
        for (int j = 0; j < 32; ++j) {                                       \
            const float wv = wr[j];                                          \
            acc0[j] = fmaf(fa, wv, acc0[j]);                                 \
            acc1[j] = fmaf(fb_, wv, acc1[j]);                                \
        }                                                                    \
    }

    int c = 0;
    #pragma unroll 1
    for (; c + 4 < C; c += 4) {
        POOL_STEP(c + 0, f0, true, c + 4)
        POOL_STEP(c + 1, f1, true, c + 5)
        POOL_STEP(c + 2, f2, true, c + 6)
        POOL_STEP(c + 3, f3, true, c + 7)
    }
    // tail: c == C-4 here, consume the last four buffers without reloading
    POOL_STEP(C - 4, f0, false, 0)
    POOL_STEP(C - 3, f1, false, 0)
    POOL_STEP(C - 2, f2, false, 0)
    POOL_STEP(C - 1, f3, false, 0)
#undef POOL_STEP

    // gelu + partial attn logits over this wave's 32 hidden units
    float pl0 = 0.f, pl1 = 0.f;
    #pragma unroll
    for (int j = 0; j < 32; ++j) {
        const float fwv = finw[wu * 32 + j];       // uniform
        pl0 = fmaf(gelu_exact(acc0[j]), fwv, pl0);
        pl1 = fmaf(gelu_exact(acc1[j]), fwv, pl1);
    }
    sPlog[wu * 128 + lane * 2]     = pl0;
    sPlog[wu * 128 + lane * 2 + 1] = pl1;
    __syncthreads();

    if (tid < 128) {                               // combine waves; px_local = tid
        float lg = finb[0] + sPlog[tid] + sPlog[128 + tid] + sPlog[256 + tid] + sPlog[384 + tid];
        int px = hw0 + tid;
        float a = (px < HW) ? 1.0f / (1.0f + expf(-lg)) : 0.0f;
        sAttn[tid] = a;
        if (WRITE_ATTN && px < HW) attn_out[bq * HW + px] = a;
        float sa = a;
        #pragma unroll
        for (int d = 1; d < 64; d <<= 1) sa += __shfl_xor(sa, d);
        if ((tid & 63) == 0) sRed[tid >> 6] = sa;
    }
    __syncthreads();
    if (tid == 0) atomicAdd(&Sout[bq * (C + 1) + C], sRed[0] + sRed[1]);

    // S_fc[c]: column-cooperative, coalesced loads, wave shfl-reduce per c
    constexpr int CPW = C / 4;
    for (int ci = 0; ci < CPW; ++ci) {
        const int cch = wu * CPW + ci;
        const float* fr = fbase + (size_t)cch * HW;
        float s = 0.f;
        #pragma unroll
        for (int k = 0; k < 2; ++k) {
            int pxi = lane + 64 * k;
            int gc = min(hw0 + pxi, HW - 1);       // sAttn==0 masks invalid px
            s = fmaf(fr[gc], sAttn[pxi], s);
        }
        #pragma unroll
        for (int d = 1; d < 64; d <<= 1) s += __shfl_xor(s, d);
        if (lane == 0) atomicAdd(&Sout[bq * (C + 1) + cch], s);
    }
}

__global__ __launch_bounds__(256, 4)
void pool_fused(const float* __restrict__ feat0, const float* __restrict__ feat1,
                const float* __restrict__ feat2,
                const float* __restrict__ gb0, const float* __restrict__ gb1,
                const float* __restrict__ gb2,
                const float* __restrict__ b20, const float* __restrict__ b21,
                const float* __restrict__ b22,
                const float* __restrict__ hw0_, const float* __restrict__ hw1_,
                const float* __restrict__ hw2_,
                const float* __restrict__ finw0, const float* __restrict__ finb0,
                const float* __restrict__ finw1, const float* __restrict__ finb1,
                const float* __restrict__ finw2, const float* __restrict__ finb2,
                float* __restrict__ S0, float* __restrict__ S1, float* __restrict__ S2,
                float* __restrict__ attn2)
{
    __shared__ float sAttn[128];
    __shared__ float sPlog[512];
    __shared__ float sRed[2];
    const int blk = blockIdx.x;
    if (blk < 256) {                               // scale 2 (heaviest) first
        int bq = blk >> 2, t = blk & 3;            // 4 tiles of 128 px (400 -> pad)
        pool_body<256, true>(feat2, 400, gb2, b22, hw2_, finw2, finb2,
                             S2, attn2, bq, t, sAttn, sPlog, sRed);
    } else if (blk < 256 + 832) {
        int bb = blk - 256; int bq = bb / 13, t = bb % 13;   // 13 tiles (1600)
        pool_body<128, false>(feat1, 1600, gb1, b21, hw1_, finw1, finb1,
                              S1, nullptr, bq, t, sAttn, sPlog, sRed);
    } else {
        int bb = blk - 1088; int bq = bb / 50, t = bb % 50;  // 50 tiles (6400)
        pool_body<64, false>(feat0, 6400, gb0, b20, hw0_, finw0, finb0,
                             S0, nullptr, bq, t, sAttn, sPlog, sRed);
    }
}

// ---------------------------------------------------------------------------
// MLP layer 1 (pre-gelu): grid (BQ, 4), 128 outputs per block, 2 thr/output
// ---------------------------------------------------------------------------
__global__ __launch_bounds__(256)
void mlp1_kernel(const float* __restrict__ S0, const float* __restrict__ S1,
                 const float* __restrict__ S2,
                 const float* __restrict__ gb0, const float* __restrict__ gb1,
                 const float* __restrict__ gb2,
                 const float* __restrict__ attn2,
                 const float* __restrict__ w1, const float* __restrict__ b1,
                 float* __restrict__ X1)
{
    __shared__ float sCat[848];
    __shared__ float sP[256];
    const int tid = threadIdx.x, bq = blockIdx.x;

    for (int i = tid; i < 448; i += 256) {
        int sc, c;
        if (i < 64)       { sc = 0; c = i; }
        else if (i < 192) { sc = 1; c = i - 64; }
        else              { sc = 2; c = i - 192; }
        const int C = 64 << sc;
        const float* So = (sc == 0) ? S0 : (sc == 1) ? S1 : S2;
        const float* g  = (sc == 0) ? gb0 : (sc == 1) ? gb1 : gb2;
        float Sa = So[bq * (C + 1) + C];
        float Sf = So[bq * (C + 1) + c];
        float gamma = g[bq * 2 * C + c];
        float beta  = g[bq * 2 * C + C + c];
        sCat[i] = (gamma * Sf + beta * Sa) / (Sa + EPS);
    }
    for (int i = tid; i < 400; i += 256) sCat[448 + i] = attn2[bq * 400 + i];
    __syncthreads();

    const int o = blockIdx.y * 128 + (tid & 127), half = tid >> 7;
    const int k0 = half * 424;
    float a0 = 0.f, a1 = 0.f;
    #pragma unroll 2
    for (int k = 0; k < 424; k += 2) {
        a0 = fmaf(sCat[k0 + k],     w1[(k0 + k) * 512 + o],     a0);
        a1 = fmaf(sCat[k0 + k + 1], w1[(k0 + k + 1) * 512 + o], a1);
    }
    sP[tid] = a0 + a1;
    __syncthreads();
    if (tid < 128) {
        int oo = blockIdx.y * 128 + tid;
        X1[bq * 512 + oo] = sP[tid] + sP[tid + 128] + b1[oo];
    }
}

// ---------------------------------------------------------------------------
// MLP layers 2+3. grid BQ, 256 threads
// ---------------------------------------------------------------------------
__global__ __launch_bounds__(256)
void mlp23_kernel(const float* __restrict__ X1,
                  const float* __restrict__ w2, const float* __restrict__ b2,
                  const float* __restrict__ w3, const float* __restrict__ b3,
                  float* __restrict__ out)
{
    __shared__ float sX1[512];
    __shared__ float sX2[256];
    __shared__ float sR[4];
    const int tid = threadIdx.x, bq = blockIdx.x;
    for (int i = tid; i < 512; i += 256) sX1[i] = gelu_exact(X1[bq * 512 + i]);
    __syncthreads();
    float a0 = b2[tid], a1 = 0.f, a2 = 0.f, a3 = 0.f;
    #pragma unroll 4
    for (int k = 0; k < 512; k += 4) {
        a0 = fmaf(sX1[k],     w2[(k)     * 256 + tid], a0);
        a1 = fmaf(sX1[k + 1], w2[(k + 1) * 256 + tid], a1);
        a2 = fmaf(sX1[k + 2], w2[(k + 2) * 256 + tid], a2);
        a3 = fmaf(sX1[k + 3], w2[(k + 3) * 256 + tid], a3);
    }
    sX2[tid] = gelu_exact((a0 + a1) + (a2 + a3));
    __syncthreads();
    float p = sX2[tid] * w3[tid];
    #pragma unroll
    for (int d = 1; d < 64; d <<= 1) p += __shfl_xor(p, d);
    if ((tid & 63) == 0) sR[tid >> 6] = p;
    __syncthreads();
    if (tid == 0) out[bq] = sR[0] + sR[1] + sR[2] + sR[3] + b3[0];
}

// ---------------------------------------------------------------------------
extern "C" void kernel_launch(void* const* d_in, const int* in_sizes, int n_in,
                              void* d_out, int out_size, void* d_ws, size_t ws_size,
                              hipStream_t stream)
{
    const float* feat0 = (const float*)d_in[0];
    const float* feat1 = (const float*)d_in[1];
    const float* feat2 = (const float*)d_in[2];
    const float* qe    = (const float*)d_in[3];
    const float* film_w0 = (const float*)d_in[4];
    const float* film_b0 = (const float*)d_in[5];
    const float* hid_w0  = (const float*)d_in[6];
    const float* hid_b0  = (const float*)d_in[7];
    const float* fin_w0  = (const float*)d_in[8];
    const float* fin_b0  = (const float*)d_in[9];
    const float* film_w1 = (const float*)d_in[10];
    const float* film_b1 = (const float*)d_in[11];
    const float* hid_w1  = (const float*)d_in[12];
    const float* hid_b1  = (const float*)d_in[13];
    const float* fin_w1  = (const float*)d_in[14];
    const float* fin_b1  = (const float*)d_in[15];
    const float* film_w2 = (const float*)d_in[16];
    const float* film_b2 = (const float*)d_in[17];
    const float* hid_w2  = (const float*)d_in[18];
    const float* hid_b2  = (const float*)d_in[19];
    const float* fin_w2  = (const float*)d_in[20];
    const float* fin_b2  = (const float*)d_in[21];
    const float* mlp_w1  = (const float*)d_in[22];
    const float* mlp_b1  = (const float*)d_in[23];
    const float* mlp_w2  = (const float*)d_in[24];
    const float* mlp_b2  = (const float*)d_in[25];
    const float* mlp_w3  = (const float*)d_in[26];
    const float* mlp_b3  = (const float*)d_in[27];

    float* ws = (float*)d_ws;
    float* S0    = ws;              // [64][65]
    float* S1    = ws + 4160;       // [64][129]
    float* S2    = ws + 12416;      // [64][257]   (Sout end 28864)
    float* gb0   = ws + 28864;      // [64][128]
    float* gb1   = ws + 37056;      // [64][256]
    float* gb2   = ws + 53440;      // [64][512]
    float* b20   = ws + 86208;      // [64][128]
    float* b21   = ws + 94400;
    float* b22   = ws + 102592;
    float* attn2 = ws + 110784;     // [64][400]
    float* X1    = ws + 136384;     // [64][512]

    hipMemsetAsync(d_ws, 0, 28864 * sizeof(float), stream);

    film2_kernel<<<dim3(BQ, 7), 256, 0, stream>>>(
        qe, film_w0, film_b0, film_w1, film_b1, film_w2, film_b2,
        gb0, gb1, gb2);

    b2_kernel<<<dim3(BQ, 3), 256, 0, stream>>>(
        gb0, gb1, gb2,
        hid_w0, hid_b0, hid_w1, hid_b1, hid_w2, hid_b2,
        b20, b21, b22);

    pool_fused<<<4288, 256, 0, stream>>>(
        feat0, feat1, feat2,
        gb0, gb1, gb2, b20, b21, b22,
        hid_w0, hid_w1, hid_w2,
        fin_w0, fin_b0, fin_w1, fin_b1, fin_w2, fin_b2,
        S0, S1, S2, attn2);

    mlp1_kernel<<<dim3(BQ, 4), 256, 0, stream>>>(
        S0, S1, S2, gb0, gb1, gb2, attn2, mlp_w1, mlp_b1, X1);

    mlp23_kernel<<<BQ, 256, 0, stream>>>(
        X1, mlp_w2, mlp_b2, mlp_w3, mlp_b3, (float*)d_out);
}